// Round 7
// baseline (18.069 us; speedup 1.0000x reference)
//
#include <hip/hip_runtime.h>
#include <math.h>

// LIF neuron Euler integration, T = 3.5M steps, scalar input current.
//
// Structural insight (verified R1-R6, absmax = 0): every spike resets v to
// exactly V_RESET = 0.0f == initial state, so the fp32 dynamics are exactly
// periodic: spikes[t] = (t > 0 && t % P == 0), P = fp32 Euler steps from v=0
// to first v_new >= 1.0f (P = 220 for I = 1.5).
//
// R7 = disambiguation of R6's bundled regression (10.71 -> 11.76):
//   keep  : R5 grid/fill shape (1024 blocks x 256 thr, ~3.3 float4
//           chunks/thread -- prologue amortized over multiple stores)
//   change: barrier-free P -- every thread computes P redundantly (fp32 HW
//           log2 seed + ~20 dependent fp64 HW mults, ~0.13 us, parallel);
//           no LDS, no __syncthreads.
// Margin check: accept closed-form P only if fp64-exact v(P-1), v(P) clear
// threshold by > 1e-4 + 4e-7*P (worst-case fp32 drift); else bit-exact
// serial fallback (contract off, reference op order,
// alpha = float(double(1e-4)/double(0.02)) == jnp.float32(DT/TAU)).

__device__ __forceinline__ unsigned lif_period_serial(float I, int n_steps) {
#pragma clang fp contract(off)
    const float alpha = (float)(1e-4 / 0.02);  // == jnp.float32(DT / TAU)
    unsigned P = 0;
    float v = 0.0f;
    for (int t = 1; t < n_steps; ++t) {
        float v_new = v + (I - v) * alpha;     // == v + (-v + I)*alpha in IEEE
        if (v_new >= 1.0f) { P = (unsigned)t; break; }
        if (v_new == v) break;                 // converged below threshold
        v = v_new;
    }
    return P;
}

__device__ __forceinline__ double pow_u(double b, unsigned e) {
    double r = 1.0, p = b;
    while (e) { if (e & 1u) r *= p; p *= p; e >>= 1; }
    return r;
}

__device__ __forceinline__ unsigned lif_period(float I, int n) {
    const float alpha_f = (float)(1e-4 / 0.02);

    if (I < 0.999f) return 0u;        // fixed point v -> I, never crosses

    if (I >= 1.001f) {
        // fp32 HW-transcendental seed (error ~5e-5 steps; need only +-1)
        const float x   = 1.0f - 1.0f / I;
        const float nn  = log2f(x) / log2f(1.0f - alpha_f);
        long m0 = (long)nn - 2;
        if (m0 < 1) m0 = 1;

        // exact margins via fp64 HW mults only (no libm)
        const double beta = 1.0 - (double)alpha_f;
        const double dI   = (double)I;
        double bm    = pow_u(beta, (unsigned)(m0 - 1));
        double vprev = dI * (1.0 - bm);
        for (long m = m0; m <= m0 + 6; ++m) {
            bm *= beta;
            double vm = dI * (1.0 - bm);
            if (vm >= 1.0) {
                const double margin = 1e-4 + 4e-7 * (double)m;
                if ((1.0 - vprev) > margin && (vm - 1.0) > margin)
                    return (unsigned)m;
                break;                // ambiguous -> serial fallback
            }
            vprev = vm;
        }
    }
    return lif_period_serial(I, n);   // bit-exact fallback
}

__global__ void lif_kernel(const float* __restrict__ input_current,
                           float* __restrict__ out, int n, int span) {
    const unsigned un = (unsigned)n;
    const unsigned lo = (unsigned)blockIdx.x * (unsigned)span;
    if (lo >= un) return;
    unsigned hi = lo + (unsigned)span;
    if (hi > un) hi = un;

    const unsigned P = lif_period(input_current[0], n);

    unsigned i0 = lo + threadIdx.x * 4u;
    const unsigned step = 256u * 4u;

    if (P == 0u) {
        const float4 z = make_float4(0.f, 0.f, 0.f, 0.f);
        for (; i0 + 4u <= hi; i0 += step)
            *reinterpret_cast<float4*>(out + i0) = z;
        for (unsigned i = i0; i < hi && i < i0 + 4u; ++i) out[i] = 0.0f;
        return;
    }

    unsigned r    = i0 % P;     // one integer division per thread
    unsigned smod = step % P;   // uniform; add-with-wrap thereafter
    for (; i0 + 4u <= hi; i0 += step) {
        float4 vals;
        unsigned rr = r;
        vals.x = (rr == 0u && i0 != 0u) ? 1.0f : 0.0f;
        rr = (rr + 1u == P) ? 0u : rr + 1u;
        vals.y = (rr == 0u) ? 1.0f : 0.0f;
        rr = (rr + 1u == P) ? 0u : rr + 1u;
        vals.z = (rr == 0u) ? 1.0f : 0.0f;
        rr = (rr + 1u == P) ? 0u : rr + 1u;
        vals.w = (rr == 0u) ? 1.0f : 0.0f;
        *reinterpret_cast<float4*>(out + i0) = vals;
        r += smod;
        if (r >= P) r -= P;
    }
    // partial tail chunk (last block only, n % 4 != 0)
    if (i0 < hi) {
        unsigned rr = r;
        for (unsigned i = i0; i < hi && i < i0 + 4u; ++i) {
            out[i] = (rr == 0u && i != 0u) ? 1.0f : 0.0f;
            rr = (rr + 1u == P) ? 0u : rr + 1u;
        }
    }
}

extern "C" void kernel_launch(void* const* d_in, const int* in_sizes, int n_in,
                              void* d_out, int out_size, void* d_ws, size_t ws_size,
                              hipStream_t stream) {
    const float* d_I = (const float*)d_in[0];   // input_current (scalar)
    float* out = (float*)d_out;                 // T fp32 spikes

    const int nblocks = 1024;
    int span = (out_size + nblocks - 1) / nblocks;
    span = (span + 3) & ~3;                     // x4-aligned spans
    lif_kernel<<<nblocks, 256, 0, stream>>>(d_I, out, out_size, span);
}

// Round 8
// 12.148 us; speedup vs baseline: 1.4875x; 1.4875x over previous
//
#include <hip/hip_runtime.h>
#include <math.h>

// LIF neuron Euler integration, T = 3.5M steps, scalar input current.
//
// Structural insight (verified R1-R7, absmax = 0): every spike resets v to
// exactly V_RESET = 0.0f == initial state, so the fp32 dynamics are exactly
// periodic: spikes[t] = (t > 0 && t % P == 0), P = fp32 Euler steps from v=0
// to first v_new >= 1.0f (P = 220 for I = 1.5).
//
// R8 = R5 verbatim (best measured: 10.71 us), as a repeat probe to separate
// session-floor drift from real kernel cost. Session dur_us is bimodal
// (~21/19/18 vs ~11.3/10.7/11.8) while all structural deltas model to
// <= 2 us -- suspect ~7 us per-replay floor drift between bench sessions.
//
// Structure: thread 0 per block computes P (fp32 HW log2 seed + fp64 HW-mult
// margin check, bit-exact serial fallback), LDS broadcast, 256 threads fill
// the block's span with float4 stores + mod-counter (one int div/thread).

__device__ __forceinline__ unsigned lif_period_serial(float I, int n_steps) {
#pragma clang fp contract(off)
    const float alpha = (float)(1e-4 / 0.02);  // == jnp.float32(DT / TAU)
    unsigned P = 0;
    float v = 0.0f;
    for (int t = 1; t < n_steps; ++t) {
        float v_new = v + (I - v) * alpha;     // == v + (-v + I)*alpha in IEEE
        if (v_new >= 1.0f) { P = (unsigned)t; break; }
        if (v_new == v) break;                 // converged below threshold
        v = v_new;
    }
    return P;
}

__device__ __forceinline__ double pow_u(double b, unsigned e) {
    double r = 1.0, p = b;
    while (e) { if (e & 1u) r *= p; p *= p; e >>= 1; }
    return r;
}

__global__ void lif_kernel(const float* __restrict__ input_current,
                           float* __restrict__ out, int n, int span) {
    __shared__ unsigned sP;

    const unsigned un = (unsigned)n;
    const unsigned lo = (unsigned)blockIdx.x * (unsigned)span;
    if (lo >= un) return;
    unsigned hi = lo + (unsigned)span;
    if (hi > un) hi = un;

    if (threadIdx.x == 0) {
        const float I       = input_current[0];
        const float alpha_f = (float)(1e-4 / 0.02);
        unsigned P = 0;
        bool resolved = false;

        if (I >= 1.001f) {
            // fp32 HW-transcendental seed (error ~5e-5 steps; need only +-1)
            const float x   = 1.0f - 1.0f / I;
            const float nn  = log2f(x) / log2f(1.0f - alpha_f);
            long m0 = (long)nn - 2;
            if (m0 < 1) m0 = 1;

            // exact margins via fp64 HW mults only (no libm)
            const double beta = 1.0 - (double)alpha_f;
            const double dI   = (double)I;
            double bm    = pow_u(beta, (unsigned)(m0 - 1));
            double vprev = dI * (1.0 - bm);
            for (long m = m0; m <= m0 + 6; ++m) {
                bm *= beta;
                double vm = dI * (1.0 - bm);
                if (vm >= 1.0) {
                    const double margin = 1e-4 + 4e-7 * (double)m;
                    if ((1.0 - vprev) > margin && (vm - 1.0) > margin) {
                        P = (unsigned)m;
                        resolved = true;
                    }
                    break;            // ambiguous -> serial fallback
                }
                vprev = vm;
            }
        } else if (I < 0.999f) {
            P = 0;                    // fixed point v -> I, never crosses
            resolved = true;
        }
        if (!resolved) P = lif_period_serial(I, n);  // bit-exact fallback
        sP = P;
    }
    __syncthreads();

    const unsigned P = sP;
    unsigned i0 = lo + threadIdx.x * 4u;
    const unsigned step = 256u * 4u;

    if (P == 0u) {
        const float4 z = make_float4(0.f, 0.f, 0.f, 0.f);
        for (; i0 + 4u <= hi; i0 += step)
            *reinterpret_cast<float4*>(out + i0) = z;
        for (unsigned i = i0; i < hi && i < i0 + 4u; ++i) out[i] = 0.0f;
        return;
    }

    unsigned r    = i0 % P;     // one integer division per thread
    unsigned smod = step % P;   // uniform; add-with-wrap thereafter
    for (; i0 + 4u <= hi; i0 += step) {
        float4 vals;
        unsigned rr = r;
        vals.x = (rr == 0u && i0 != 0u) ? 1.0f : 0.0f;
        rr = (rr + 1u == P) ? 0u : rr + 1u;
        vals.y = (rr == 0u) ? 1.0f : 0.0f;
        rr = (rr + 1u == P) ? 0u : rr + 1u;
        vals.z = (rr == 0u) ? 1.0f : 0.0f;
        rr = (rr + 1u == P) ? 0u : rr + 1u;
        vals.w = (rr == 0u) ? 1.0f : 0.0f;
        *reinterpret_cast<float4*>(out + i0) = vals;
        r += smod;
        if (r >= P) r -= P;
    }
    // partial tail chunk (last block only, n % 4 != 0)
    if (i0 < hi) {
        unsigned rr = r;
        for (unsigned i = i0; i < hi && i < i0 + 4u; ++i) {
            out[i] = (rr == 0u && i != 0u) ? 1.0f : 0.0f;
            rr = (rr + 1u == P) ? 0u : rr + 1u;
        }
    }
}

extern "C" void kernel_launch(void* const* d_in, const int* in_sizes, int n_in,
                              void* d_out, int out_size, void* d_ws, size_t ws_size,
                              hipStream_t stream) {
    const float* d_I = (const float*)d_in[0];   // input_current (scalar)
    float* out = (float*)d_out;                 // T fp32 spikes

    const int nblocks = 1024;
    int span = (out_size + nblocks - 1) / nblocks;
    span = (span + 3) & ~3;                     // x4-aligned spans
    lif_kernel<<<nblocks, 256, 0, stream>>>(d_I, out, out_size, span);
}